// Round 8
// baseline (132.674 us; speedup 1.0000x reference)
//
#include <hip/hip_runtime.h>
#include <stdint.h>

#define JAX_PARTITIONABLE 1

constexpr int N = 4096;
constexpr int DIM = 64;
constexpr int TOPK = 5;
constexpr int NEGS = 20;
constexpr float TAU_ = 0.1f;
constexpr uint32_t SPAN = 4091u;   // N - TOPK
constexpr uint32_t MULT = 2309u;   // ((1<<16) % SPAN)^2 % SPAN

constexpr int CQ = 256;            // cols per wave slab
constexpr int NQ = N / CQ;         // 16 col groups
constexpr int NT = CQ / 16;        // 16 tiles per wave

typedef __attribute__((ext_vector_type(8))) short bf16x8;
typedef __attribute__((ext_vector_type(4))) float f32x4;

__device__ __forceinline__ uint32_t rotl32(uint32_t v, int d) {
  return (v << d) | (v >> (32 - d));
}

// Threefry-2x32, 20 rounds, exactly as jax/_src/prng.py lowering.
__device__ __forceinline__ void threefry(uint32_t k0, uint32_t k1,
                                         uint32_t& x0, uint32_t& x1) {
  const uint32_t k2 = k0 ^ k1 ^ 0x1BD11BDAu;
  x0 += k0; x1 += k1;
#define TF_R(r) { x0 += x1; x1 = rotl32(x1, r); x1 ^= x0; }
  TF_R(13) TF_R(15) TF_R(26) TF_R(6)
  x0 += k1; x1 += k2 + 1u;
  TF_R(17) TF_R(29) TF_R(16) TF_R(24)
  x0 += k2; x1 += k0 + 2u;
  TF_R(13) TF_R(15) TF_R(26) TF_R(6)
  x0 += k0; x1 += k1 + 3u;
  TF_R(17) TF_R(29) TF_R(16) TF_R(24)
  x0 += k1; x1 += k2 + 4u;
  TF_R(13) TF_R(15) TF_R(26) TF_R(6)
  x0 += k2; x1 += k0 + 5u;
#undef TF_R
}

__device__ __forceinline__ uint32_t sample_idx(uint32_t seed, uint32_t f) {
#if JAX_PARTITIONABLE
  uint32_t a0 = 0u, a1 = 0u; threefry(0u, seed, a0, a1);   // k1 = enc(key,(0,0))
  uint32_t b0 = 0u, b1 = 1u; threefry(0u, seed, b0, b1);   // k2 = enc(key,(0,1))
  uint32_t h0 = 0u, h1 = f;  threefry(a0, a1, h0, h1);
  const uint32_t hi = h0 ^ h1;
  uint32_t l0 = 0u, l1 = f;  threefry(b0, b1, l0, l1);
  const uint32_t lo = l0 ^ l1;
#else
  uint32_t a0 = 0u, a1 = 2u; threefry(0u, seed, a0, a1);
  uint32_t c0 = 1u, c1 = 3u; threefry(0u, seed, c0, c1);
  const uint32_t HALF = (uint32_t)(N * NEGS / 2);
  uint32_t hi, lo;
  if (f < HALF) {
    uint32_t x0 = f, x1 = f + HALF; threefry(a0, c0, x0, x1); hi = x0;
    x0 = f; x1 = f + HALF;          threefry(a1, c1, x0, x1); lo = x0;
  } else {
    uint32_t x0 = f - HALF, x1 = f; threefry(a0, c0, x0, x1); hi = x1;
    x0 = f - HALF; x1 = f;          threefry(a1, c1, x0, x1); lo = x1;
  }
#endif
  return ((hi % SPAN) * MULT + (lo % SPAN)) % SPAN;
}

__device__ __forceinline__ float acosh_dev(float z) {
  return logf(z + sqrtf((z - 1.0f) * (z + 1.0f)));
}

__device__ __forceinline__ uint16_t f2bf(float f) {   // RNE f32 -> bf16
  const uint32_t u = __float_as_uint(f);
  return (uint16_t)((u + 0x7FFFu + ((u >> 16) & 1u)) >> 16);
}
__device__ __forceinline__ float bf2f(uint16_t h) {
  return __uint_as_float((uint32_t)h << 16);
}

// K_pre: per row: exact f32 norms + inv, and bf16 hi/lo split rows
// Xs layout: [mod][row][128 u16] = hi[64] | lo[64], row stride 256 B.
__global__ __launch_bounds__(64) void k_pre(const float* __restrict__ Xa,
                                            const float* __restrict__ Xt,
                                            uint16_t* __restrict__ Xs,
                                            float* __restrict__ ysq,
                                            float* __restrict__ inv) {
  const int m = blockIdx.y;                  // 0 = text, 1 = audio
  const float* __restrict__ X = (m == 0) ? Xt : Xa;
  const int i = blockIdx.x * 64 + threadIdx.x;
  const float* xr = X + (size_t)i * DIM;

  uint32_t hb[DIM / 2], lb[DIM / 2];
  float s = 0.0f;
#pragma unroll
  for (int u = 0; u < DIM / 4; ++u) {
    const float4 v = *(const float4*)(xr + 4 * u);
    s = fmaf(v.x, v.x, s); s = fmaf(v.y, v.y, s);
    s = fmaf(v.z, v.z, s); s = fmaf(v.w, v.w, s);
    const uint16_t h0 = f2bf(v.x), h1 = f2bf(v.y), h2 = f2bf(v.z), h3 = f2bf(v.w);
    const uint16_t l0 = f2bf(v.x - bf2f(h0)), l1 = f2bf(v.y - bf2f(h1));
    const uint16_t l2 = f2bf(v.z - bf2f(h2)), l3 = f2bf(v.w - bf2f(h3));
    hb[2 * u]     = (uint32_t)h0 | ((uint32_t)h1 << 16);
    hb[2 * u + 1] = (uint32_t)h2 | ((uint32_t)h3 << 16);
    lb[2 * u]     = (uint32_t)l0 | ((uint32_t)l1 << 16);
    lb[2 * u + 1] = (uint32_t)l2 | ((uint32_t)l3 << 16);
  }
  uint32_t* dst = (uint32_t*)(Xs + (size_t)(m * N + i) * 128);
#pragma unroll
  for (int w = 0; w < 8; ++w) {
    uint4 qh = { hb[4 * w], hb[4 * w + 1], hb[4 * w + 2], hb[4 * w + 3] };
    ((uint4*)dst)[w] = qh;
  }
#pragma unroll
  for (int w = 0; w < 8; ++w) {
    uint4 ql = { lb[4 * w], lb[4 * w + 1], lb[4 * w + 2], lb[4 * w + 3] };
    ((uint4*)dst)[8 + w] = ql;
  }
  ysq[m * N + i] = s;
  inv[m * N + i] = 1.0f / (1.0f - fminf(s, 1.0f));
}

// K1: MFMA pairwise-z + per-row top-5 partials (swapped-operand layout),
// software-pipelined: E/O double-buffered Y fragments + sq/iv prefetch so
// every tile's loads have >=1 tile of compute (x resident waves) to hide
// under (round-6 had a serial load->use chain: ~1740cyc/tile, latency-bound).
// Lane owns ONE output row (lc) and 4 cols (lk4+p); one top-5 list/thread.
__global__ __launch_bounds__(128) void k_top5(
    const uint16_t* __restrict__ Xs, const float* __restrict__ ysq,
    const float* __restrict__ inv, uint64_t* __restrict__ partial) {
  const int m = blockIdx.z;
  const int qq = blockIdx.y;
  const int wid = (int)threadIdx.x >> 6;
  const int l = (int)threadIdx.x & 63;
  const int i0 = (blockIdx.x * 2 + wid) * 16;
  const int j0q = qq * CQ;
  const int mN = m * N;
  const uint16_t* __restrict__ Xm = Xs + (size_t)m * N * 128;
  const int lc = l & 15;          // output row index (this lane's row)
  const int lk = l >> 4;
  const int lk4 = lk * 4;         // candidate-col base for this lane
  const int lk8 = lk * 8;         // u16 offset of this lane's 8 bf16 (k-slice)

  // B operand: X rows (fixed): xf[k-chunk][hi/lo]
  bf16x8 xf[2][2];
#pragma unroll
  for (int c = 0; c < 2; ++c)
#pragma unroll
    for (int h = 0; h < 2; ++h)
      xf[c][h] = *(const bf16x8*)(Xm + (size_t)(i0 + lc) * 128 +
                                  h * 64 + c * 32 + lk8);

  const float xsq_i = ysq[mN + i0 + lc];
  const float inv2_i = 2.0f * inv[mN + i0 + lc];   // exact x2: z bits unchanged
  const int gi = i0 + lc;

  // sentinel: z=+inf, idx=0xFFFFFFFF
  const uint64_t SENT = ((uint64_t)0x7F800000u << 32) | 0xFFFFFFFFu;
  uint64_t t5[TOPK];
#pragma unroll
  for (int t = 0; t < TOPK; ++t) t5[t] = SENT;

  const f32x4 zz = {0.0f, 0.0f, 0.0f, 0.0f};
  const float INF_ = __uint_as_float(0x7F800000u);

  // per-tile streaming pointers (tile stride: 16 rows * 128 u16 = 2048)
  const uint16_t* __restrict__ yp = Xm + (size_t)(j0q + lc) * 128 + lk8;
  const float* __restrict__ sqp = ysq + mN + j0q + lk4;
  const float* __restrict__ ivp = inv + mN + j0q + lk4;

#define LOADY(Y, T)                                                            \
  {                                                                            \
    const uint16_t* p_ = yp + (size_t)(T) * 2048;                              \
    Y[0] = *(const bf16x8*)(p_);                                               \
    Y[1] = *(const bf16x8*)(p_ + 32);                                          \
    Y[2] = *(const bf16x8*)(p_ + 64);                                          \
    Y[3] = *(const bf16x8*)(p_ + 96);                                          \
  }
#define LOADSI(SQ, IV, T)                                                      \
  {                                                                            \
    SQ = *(const float4*)(sqp + (T) * 16);                                     \
    IV = *(const float4*)(ivp + (T) * 16);                                     \
  }

  // same term order as rounds 3-6 (bit-exact z)
#define MFMA_TILE(ACC, Y)                                                      \
  {                                                                            \
    ACC = __builtin_amdgcn_mfma_f32_16x16x32_bf16(Y[0], xf[0][0], zz, 0, 0, 0);  \
    ACC = __builtin_amdgcn_mfma_f32_16x16x32_bf16(Y[1], xf[1][0], ACC, 0, 0, 0); \
    ACC = __builtin_amdgcn_mfma_f32_16x16x32_bf16(Y[2], xf[0][0], ACC, 0, 0, 0); \
    ACC = __builtin_amdgcn_mfma_f32_16x16x32_bf16(Y[3], xf[1][0], ACC, 0, 0, 0); \
    ACC = __builtin_amdgcn_mfma_f32_16x16x32_bf16(Y[0], xf[0][1], ACC, 0, 0, 0); \
    ACC = __builtin_amdgcn_mfma_f32_16x16x32_bf16(Y[1], xf[1][1], ACC, 0, 0, 0); \
  }

#define EPILOG(T, ACC, SQ4, IV4)                                               \
  {                                                                            \
    /* exact screen: tau = min 5th-best over the row's 4 lk-lanes */           \
    float w_ = __uint_as_float((uint32_t)(t5[TOPK - 1] >> 32));                \
    w_ = fminf(w_, __shfl_xor(w_, 16, 64));                                    \
    const float tau_ = fminf(w_, __shfl_xor(w_, 32, 64));                      \
    const int jb_ = j0q + (T) * 16;                                            \
    float zt_[4];                                                              \
    _Pragma("unroll") for (int p = 0; p < 4; ++p) {                            \
      const float yc_ = (p == 0) ? SQ4.x : (p == 1) ? SQ4.y                    \
                       : (p == 2) ? SQ4.z : SQ4.w;                             \
      const float ic_ = (p == 0) ? IV4.x : (p == 1) ? IV4.y                    \
                       : (p == 2) ? IV4.z : IV4.w;                             \
      const float diff_ = fmaxf(xsq_i + yc_ - 2.0f * ACC[p], 0.0f);            \
      const float z_ = fmaf(diff_ * inv2_i, ic_, 1.0f);                        \
      zt_[p] = (gi == jb_ + lk4 + p) ? INF_ : z_;                              \
    }                                                                          \
    const float zm_ = fminf(fminf(zt_[0], zt_[1]), fminf(zt_[2], zt_[3]));     \
    if (zm_ <= tau_) {                                                         \
      _Pragma("unroll") for (int p = 0; p < 4; ++p) {                          \
        uint64_t key = ((uint64_t)__float_as_uint(zt_[p]) << 32) |             \
                       (uint32_t)(jb_ + lk4 + p);                              \
        if (key < t5[TOPK - 1]) {                                              \
          _Pragma("unroll") for (int tt = 0; tt < TOPK; ++tt) {                \
            const uint64_t cv = t5[tt];                                        \
            if (key < cv) { t5[tt] = key; key = cv; }                          \
          }                                                                    \
        }                                                                      \
      }                                                                        \
    }                                                                          \
  }

  bf16x8 yE[4], yO[4];
  float4 sqE, ivE, sqO, ivO;
  f32x4 acc;

  LOADY(yE, 0) LOADSI(sqE, ivE, 0)
  LOADY(yO, 1) LOADSI(sqO, ivO, 1)

#pragma unroll 1
  for (int T = 0; T < NT; T += 2) {
    MFMA_TILE(acc, yE)
    if (T + 2 < NT) LOADY(yE, T + 2)          // prefetch while EPILOG runs
    EPILOG(T, acc, sqE, ivE)
    if (T + 2 < NT) LOADSI(sqE, ivE, T + 2)
    MFMA_TILE(acc, yO)
    if (T + 3 < NT) LOADY(yO, T + 3)
    EPILOG(T + 1, acc, sqO, ivO)
    if (T + 3 < NT) LOADSI(sqO, ivO, T + 3)
  }
#undef LOADY
#undef LOADSI
#undef MFMA_TILE
#undef EPILOG

  // merge: row lc has 4 lists (lanes lk*16+lc).  LDS: [wave][row][4*5+1]
  __shared__ uint64_t mbuf[2][16][21];
#pragma unroll
  for (int t = 0; t < TOPK; ++t) mbuf[wid][lc][lk * TOPK + t] = t5[t];
  __syncthreads();

  if (l < 16) {
    uint64_t cur[TOPK];
#pragma unroll
    for (int t = 0; t < TOPK; ++t) cur[t] = mbuf[wid][l][t];
    for (int c = 1; c < 4; ++c) {
      for (int t = 0; t < TOPK; ++t) {
        uint64_t key = mbuf[wid][l][c * TOPK + t];
        if (key >= cur[TOPK - 1]) break;   // lists sorted ascending
#pragma unroll
        for (int u = 0; u < TOPK; ++u) {
          const uint64_t cv = cur[u];
          if (key < cv) { cur[u] = key; key = cv; }
        }
      }
    }
#pragma unroll
    for (int t = 0; t < TOPK; ++t)
      partial[((size_t)(m * NQ + qq) * N + i0 + l) * TOPK + t] = cur[t];
  }
}

// K2: merge slab-partials -> top5; exact f32 pos_term recompute;
// threefry sampling + exact negative distances + logsumexp.
__global__ __launch_bounds__(64) void k_neg(const float* __restrict__ Xa,
                                            const float* __restrict__ Xt,
                                            const float* __restrict__ ysq,
                                            const float* __restrict__ inv,
                                            const uint64_t* __restrict__ partial,
                                            float* __restrict__ rowres) {
  const int m = blockIdx.y;
  const int i = blockIdx.x;
  const float* __restrict__ X = (m == 0) ? Xt : Xa;
  const uint32_t seed = (m == 0) ? 1u : 2u;  // key(1)=text, key(2)=audio
  const int lane = threadIdx.x;

  __shared__ float4 xi4[DIM / 4];
  __shared__ float posv[TOPK];
  if (lane < DIM / 4) xi4[lane] = ((const float4*)(X + (size_t)i * DIM))[lane];
  __syncthreads();

  // merge NQ sorted lists (uniform across lanes)
  uint64_t cur[TOPK];
#pragma unroll
  for (int t = 0; t < TOPK; ++t)
    cur[t] = partial[((size_t)(m * NQ) * N + i) * TOPK + t];
  for (int q = 1; q < NQ; ++q) {
    for (int t = 0; t < TOPK; ++t) {
      uint64_t key = partial[((size_t)(m * NQ + q) * N + i) * TOPK + t];
      if (key >= cur[TOPK - 1]) break;
#pragma unroll
      for (int u = 0; u < TOPK; ++u) {
        const uint64_t cv = cur[u];
        if (key < cv) { cur[u] = key; key = cv; }
      }
    }
  }

  const float ysq_i = ysq[m * N + i];
  const float inv_i = inv[m * N + i];

  // lanes 32..36: exact f32 distance for the 5 selected positives
  if (lane >= 32 && lane < 32 + TOPK) {
    const int t = lane - 32;
    const uint32_t c = (uint32_t)(cur[t] & 0xffffffffu);
    const float4* xc = (const float4*)(X + (size_t)c * DIM);
    float dot = 0.0f;
#pragma unroll
    for (int k = 0; k < DIM / 4; ++k) {
      const float4 a = xi4[k];
      const float4 b = xc[k];
      dot = fmaf(a.x, b.x, dot); dot = fmaf(a.y, b.y, dot);
      dot = fmaf(a.z, b.z, dot); dot = fmaf(a.w, b.w, dot);
    }
    const float diff = fmaxf(ysq_i + ysq[m * N + c] - 2.0f * dot, 0.0f);
    const float z = 1.0f + 2.0f * diff * inv_i * inv[m * N + c];
    posv[t] = -acosh_dev(z) / TAU_;
  }

  uint32_t pidx[TOPK];
#pragma unroll
  for (int t = 0; t < TOPK; ++t) pidx[t] = (uint32_t)(cur[t] & 0xffffffffu);

#define CSWAP(a, b)                                                           \
  { const uint32_t mn = pidx[a] < pidx[b] ? pidx[a] : pidx[b];                \
    const uint32_t mx = pidx[a] < pidx[b] ? pidx[b] : pidx[a];                \
    pidx[a] = mn; pidx[b] = mx; }
  CSWAP(0, 1) CSWAP(3, 4) CSWAP(2, 4) CSWAP(2, 3) CSWAP(1, 4)
  CSWAP(0, 3) CSWAP(0, 2) CSWAP(1, 3) CSWAP(1, 2)
#undef CSWAP

  float v = -1e30f;
  if (lane < NEGS) {
    const uint32_t f = (uint32_t)i * (uint32_t)NEGS + (uint32_t)lane;
    uint32_t c = sample_idx(seed, f);
#pragma unroll
    for (int t = 0; t < TOPK; ++t) c += (c >= pidx[t]) ? 1u : 0u;
    if (c != (uint32_t)i) {
      const float4* xc = (const float4*)(X + (size_t)c * DIM);
      float dot = 0.0f;
#pragma unroll
      for (int k = 0; k < DIM / 4; ++k) {
        const float4 a = xi4[k];
        const float4 b = xc[k];
        dot = fmaf(a.x, b.x, dot); dot = fmaf(a.y, b.y, dot);
        dot = fmaf(a.z, b.z, dot); dot = fmaf(a.w, b.w, dot);
      }
      const float diff = fmaxf(ysq_i + ysq[m * N + c] - 2.0f * dot, 0.0f);
      const float z = 1.0f + 2.0f * diff * inv_i * inv[m * N + c];
      v = -acosh_dev(z) / TAU_;
    }
  }

  __syncthreads();   // posv visible

  float vmax = v;
#pragma unroll
  for (int o = 32; o > 0; o >>= 1) vmax = fmaxf(vmax, __shfl_xor(vmax, o, 64));
  float e = expf(v - vmax);
  float ss = e;
#pragma unroll
  for (int o = 32; o > 0; o >>= 1) ss += __shfl_xor(ss, o, 64);

  if (lane == 0) {
    float vm = -1e30f;
#pragma unroll
    for (int t = 0; t < TOPK; ++t) vm = fmaxf(vm, posv[t]);
    float ps = 0.0f;
#pragma unroll
    for (int t = 0; t < TOPK; ++t) ps += expf(posv[t] - vm);
    const float pos = vm + logf(ps);
    rowres[m * N + i] = (vmax + logf(ss)) - pos;
  }
}

// K3: deterministic final reduce (f64 accumulation), out = 0.01 * mean
__global__ __launch_bounds__(256) void k_reduce(const float* __restrict__ rowres,
                                                float* __restrict__ out) {
  __shared__ double sh[256];
  double s = 0.0;
  for (int idx = threadIdx.x; idx < 2 * N; idx += 256) s += (double)rowres[idx];
  sh[threadIdx.x] = s;
  __syncthreads();
  for (int o = 128; o > 0; o >>= 1) {
    if (threadIdx.x < o) sh[threadIdx.x] += sh[threadIdx.x + o];
    __syncthreads();
  }
  if (threadIdx.x == 0) out[0] = (float)(0.01 * (sh[0] / (double)N));
}

extern "C" void kernel_launch(void* const* d_in, const int* in_sizes, int n_in,
                              void* d_out, int out_size, void* d_ws,
                              size_t ws_size, hipStream_t stream) {
  const float* Xa = (const float*)d_in[0];   // audio_embeds
  const float* Xt = (const float*)d_in[1];   // text_embeds
  float* out = (float*)d_out;

  // ws layout (~7.4 MB): ysq[2N] | inv[2N] | partial[2*NQ*N*5 u64] | rowres[2N]
  //                      | Xs[2*N*128 u16]
  float* ysq = (float*)d_ws;
  float* inv = ysq + 2 * N;
  uint64_t* partial = (uint64_t*)(inv + 2 * N);
  float* rowres = (float*)(partial + (size_t)2 * NQ * N * TOPK);
  uint16_t* Xs = (uint16_t*)(rowres + 2 * N);

  k_pre<<<dim3(N / 64, 2), 64, 0, stream>>>(Xa, Xt, Xs, ysq, inv);
  k_top5<<<dim3(N / 32, NQ, 2), 128, 0, stream>>>(Xs, ysq, inv, partial);
  k_neg<<<dim3(N, 2), 64, 0, stream>>>(Xa, Xt, ysq, inv, partial, rowres);
  k_reduce<<<1, 256, 0, stream>>>(rowres, out);
}

// Round 9
// 107.112 us; speedup vs baseline: 1.2386x; 1.2386x over previous
//
#include <hip/hip_runtime.h>
#include <stdint.h>

#define JAX_PARTITIONABLE 1

constexpr int N = 4096;
constexpr int DIM = 64;
constexpr int TOPK = 5;
constexpr int NEGS = 20;
constexpr float TAU_ = 0.1f;
constexpr uint32_t SPAN = 4091u;   // N - TOPK
constexpr uint32_t MULT = 2309u;   // ((1<<16) % SPAN)^2 % SPAN

constexpr int CQ = 256;            // cols per block slab
constexpr int NQ = N / CQ;         // 16 col groups
constexpr int NT = CQ / 16;        // 16 tiles per slab
constexpr int RPB = 64;            // rows per block (4 waves x 16)
constexpr int YSTRIDE = 136;       // padded LDS row stride in u16 (272 B)

typedef __attribute__((ext_vector_type(8))) short bf16x8;
typedef __attribute__((ext_vector_type(4))) float f32x4;

__device__ __forceinline__ uint32_t rotl32(uint32_t v, int d) {
  return (v << d) | (v >> (32 - d));
}

// Threefry-2x32, 20 rounds, exactly as jax/_src/prng.py lowering.
__device__ __forceinline__ void threefry(uint32_t k0, uint32_t k1,
                                         uint32_t& x0, uint32_t& x1) {
  const uint32_t k2 = k0 ^ k1 ^ 0x1BD11BDAu;
  x0 += k0; x1 += k1;
#define TF_R(r) { x0 += x1; x1 = rotl32(x1, r); x1 ^= x0; }
  TF_R(13) TF_R(15) TF_R(26) TF_R(6)
  x0 += k1; x1 += k2 + 1u;
  TF_R(17) TF_R(29) TF_R(16) TF_R(24)
  x0 += k2; x1 += k0 + 2u;
  TF_R(13) TF_R(15) TF_R(26) TF_R(6)
  x0 += k0; x1 += k1 + 3u;
  TF_R(17) TF_R(29) TF_R(16) TF_R(24)
  x0 += k1; x1 += k2 + 4u;
  TF_R(13) TF_R(15) TF_R(26) TF_R(6)
  x0 += k2; x1 += k0 + 5u;
#undef TF_R
}

__device__ __forceinline__ uint32_t sample_idx(uint32_t seed, uint32_t f) {
#if JAX_PARTITIONABLE
  uint32_t a0 = 0u, a1 = 0u; threefry(0u, seed, a0, a1);   // k1 = enc(key,(0,0))
  uint32_t b0 = 0u, b1 = 1u; threefry(0u, seed, b0, b1);   // k2 = enc(key,(0,1))
  uint32_t h0 = 0u, h1 = f;  threefry(a0, a1, h0, h1);
  const uint32_t hi = h0 ^ h1;
  uint32_t l0 = 0u, l1 = f;  threefry(b0, b1, l0, l1);
  const uint32_t lo = l0 ^ l1;
#else
  uint32_t a0 = 0u, a1 = 2u; threefry(0u, seed, a0, a1);
  uint32_t c0 = 1u, c1 = 3u; threefry(0u, seed, c0, c1);
  const uint32_t HALF = (uint32_t)(N * NEGS / 2);
  uint32_t hi, lo;
  if (f < HALF) {
    uint32_t x0 = f, x1 = f + HALF; threefry(a0, c0, x0, x1); hi = x0;
    x0 = f; x1 = f + HALF;          threefry(a1, c1, x0, x1); lo = x0;
  } else {
    uint32_t x0 = f - HALF, x1 = f; threefry(a0, c0, x0, x1); hi = x1;
    x0 = f - HALF; x1 = f;          threefry(a1, c1, x0, x1); lo = x1;
  }
#endif
  return ((hi % SPAN) * MULT + (lo % SPAN)) % SPAN;
}

__device__ __forceinline__ float acosh_dev(float z) {
  return logf(z + sqrtf((z - 1.0f) * (z + 1.0f)));
}

__device__ __forceinline__ uint16_t f2bf(float f) {   // RNE f32 -> bf16
  const uint32_t u = __float_as_uint(f);
  return (uint16_t)((u + 0x7FFFu + ((u >> 16) & 1u)) >> 16);
}
__device__ __forceinline__ float bf2f(uint16_t h) {
  return __uint_as_float((uint32_t)h << 16);
}

// K_pre: per row: exact f32 norms + inv, and bf16 hi/lo split rows
// Xs layout: [mod][row][128 u16] = hi[64] | lo[64], row stride 256 B.
__global__ __launch_bounds__(64) void k_pre(const float* __restrict__ Xa,
                                            const float* __restrict__ Xt,
                                            uint16_t* __restrict__ Xs,
                                            float* __restrict__ ysq,
                                            float* __restrict__ inv) {
  const int m = blockIdx.y;                  // 0 = text, 1 = audio
  const float* __restrict__ X = (m == 0) ? Xt : Xa;
  const int i = blockIdx.x * 64 + threadIdx.x;
  const float* xr = X + (size_t)i * DIM;

  uint32_t hb[DIM / 2], lb[DIM / 2];
  float s = 0.0f;
#pragma unroll
  for (int u = 0; u < DIM / 4; ++u) {
    const float4 v = *(const float4*)(xr + 4 * u);
    s = fmaf(v.x, v.x, s); s = fmaf(v.y, v.y, s);
    s = fmaf(v.z, v.z, s); s = fmaf(v.w, v.w, s);
    const uint16_t h0 = f2bf(v.x), h1 = f2bf(v.y), h2 = f2bf(v.z), h3 = f2bf(v.w);
    const uint16_t l0 = f2bf(v.x - bf2f(h0)), l1 = f2bf(v.y - bf2f(h1));
    const uint16_t l2 = f2bf(v.z - bf2f(h2)), l3 = f2bf(v.w - bf2f(h3));
    hb[2 * u]     = (uint32_t)h0 | ((uint32_t)h1 << 16);
    hb[2 * u + 1] = (uint32_t)h2 | ((uint32_t)h3 << 16);
    lb[2 * u]     = (uint32_t)l0 | ((uint32_t)l1 << 16);
    lb[2 * u + 1] = (uint32_t)l2 | ((uint32_t)l3 << 16);
  }
  uint32_t* dst = (uint32_t*)(Xs + (size_t)(m * N + i) * 128);
#pragma unroll
  for (int w = 0; w < 8; ++w) {
    uint4 qh = { hb[4 * w], hb[4 * w + 1], hb[4 * w + 2], hb[4 * w + 3] };
    ((uint4*)dst)[w] = qh;
  }
#pragma unroll
  for (int w = 0; w < 8; ++w) {
    uint4 ql = { lb[4 * w], lb[4 * w + 1], lb[4 * w + 2], lb[4 * w + 3] };
    ((uint4*)dst)[8 + w] = ql;
  }
  ysq[m * N + i] = s;
  inv[m * N + i] = 1.0f / (1.0f - fminf(s, 1.0f));
}

// K1: MFMA pairwise-z + per-row top-5 partials.
// 4-wave block: 64 rows x 256-col slab. Y tiles staged cooperatively in LDS
// (1 coalesced 16B global load/thread/tile, double-buffered, T14 split) and
// consumed by all 4 waves via ds_read_b128 (padded stride 272B -> 2-way=free).
// Lane owns ONE output row (lc) and 4 cols (lk4+p); one u64 top-5 list/thread.
// Diagonal check hoisted to the single wave-uniform tile jb==i0w.
__global__ __launch_bounds__(256) void k_top5(
    const uint16_t* __restrict__ Xs, const float* __restrict__ ysq,
    const float* __restrict__ inv, uint64_t* __restrict__ partial) {
  // bijective XCD swizzle over 2048 blocks (2048 % 8 == 0)
  const int lin = (int)blockIdx.x;
  const int wg = ((lin & 7) << 8) | (lin >> 3);
  const int m = wg >> 10;               // 2
  const int qq = (wg >> 6) & 15;        // 16 col slabs
  const int rb = wg & 63;               // 64 row blocks

  const int tid = (int)threadIdx.x;
  const int wid = tid >> 6;
  const int l = tid & 63;
  const int i0w = rb * RPB + wid * 16;  // this wave's 16 rows
  const int j0q = qq * CQ;
  const int mN = m * N;
  const uint16_t* __restrict__ Xm = Xs + (size_t)m * N * 128;
  const int lc = l & 15;                // output row index within wave
  const int lk = l >> 4;
  const int lk4 = lk * 4;               // candidate-col base
  const int lk8 = lk * 8;               // u16 k-slice offset
  const int sr = tid >> 4;              // staging row (0..15)
  const int sc8 = (tid & 15) * 8;       // staging seg (u16 units, 16B)

  // LDS: y dbuf 2x16x136 u16 (8704B) | sq 256 f32 | iv 256 f32 = 10752B.
  // mbuf [4][16][21] u64 (10752B) aliases the whole thing after streaming.
  __shared__ __align__(16) unsigned char smem[2 * 16 * YSTRIDE * 2 + 2048];
  uint16_t* y0 = (uint16_t*)smem;
  uint16_t* y1 = y0 + 16 * YSTRIDE;
  float* sq_s = (float*)(smem + 2 * 16 * YSTRIDE * 2);
  float* iv_s = sq_s + CQ;

  // A fragments (this wave's rows): xf[k-chunk][hi/lo]
  bf16x8 xf[2][2];
#pragma unroll
  for (int c = 0; c < 2; ++c)
#pragma unroll
    for (int h = 0; h < 2; ++h)
      xf[c][h] = *(const bf16x8*)(Xm + (size_t)(i0w + lc) * 128 +
                                  h * 64 + c * 32 + lk8);

  const float xsq_i = ysq[mN + i0w + lc];
  const float inv2_i = 2.0f * inv[mN + i0w + lc];
  const int gi = i0w + lc;

  const uint64_t SENT = ((uint64_t)0x7F800000u << 32) | 0xFFFFFFFFu;
  uint64_t t5[TOPK];
#pragma unroll
  for (int t = 0; t < TOPK; ++t) t5[t] = SENT;

  const f32x4 zz = {0.0f, 0.0f, 0.0f, 0.0f};
  const float INF_ = __uint_as_float(0x7F800000u);

  {  // prologue: stage sq/iv slab + tile 0
    if (tid < 64)
      *(float4*)&sq_s[tid * 4] = *(const float4*)&ysq[mN + j0q + tid * 4];
    else if (tid < 128)
      *(float4*)&iv_s[(tid - 64) * 4] =
          *(const float4*)&inv[mN + j0q + (tid - 64) * 4];
    const uint4 s0 =
        *(const uint4*)(Xm + (size_t)(j0q + sr) * 128 + sc8);
    *(uint4*)(y0 + sr * YSTRIDE + sc8) = s0;
    __syncthreads();
  }

#pragma unroll 1
  for (int T = 0; T < NT; ++T) {
    const bool have_next = (T + 1 < NT);
    uint4 stg;
    if (have_next)   // issue next-tile global load early (T14 split)
      stg = *(const uint4*)(Xm + (size_t)(j0q + (T + 1) * 16 + sr) * 128 + sc8);

    const uint16_t* yp = ((T & 1) ? y1 : y0) + lc * YSTRIDE + lk8;
    const bf16x8 Y0 = *(const bf16x8*)(yp);
    const bf16x8 Y1 = *(const bf16x8*)(yp + 32);
    const bf16x8 Y2 = *(const bf16x8*)(yp + 64);
    const bf16x8 Y3 = *(const bf16x8*)(yp + 96);

    // same term order as rounds 3-7 (bit-exact z)
    f32x4 acc;
    acc = __builtin_amdgcn_mfma_f32_16x16x32_bf16(Y0, xf[0][0], zz, 0, 0, 0);
    acc = __builtin_amdgcn_mfma_f32_16x16x32_bf16(Y1, xf[1][0], acc, 0, 0, 0);
    acc = __builtin_amdgcn_mfma_f32_16x16x32_bf16(Y2, xf[0][0], acc, 0, 0, 0);
    acc = __builtin_amdgcn_mfma_f32_16x16x32_bf16(Y3, xf[1][0], acc, 0, 0, 0);
    acc = __builtin_amdgcn_mfma_f32_16x16x32_bf16(Y0, xf[0][1], acc, 0, 0, 0);
    acc = __builtin_amdgcn_mfma_f32_16x16x32_bf16(Y1, xf[1][1], acc, 0, 0, 0);

    const float4 sq4 = *(const float4*)&sq_s[T * 16 + lk4];
    const float4 iv4 = *(const float4*)&iv_s[T * 16 + lk4];
    const int jb = j0q + T * 16;

    // exact screen: tau = min 5th-best over the row's 4 lk-lanes
    float w_ = __uint_as_float((uint32_t)(t5[TOPK - 1] >> 32));
    w_ = fminf(w_, __shfl_xor(w_, 16, 64));
    const float tau_ = fminf(w_, __shfl_xor(w_, 32, 64));

    float zt[4];
#pragma unroll
    for (int p = 0; p < 4; ++p) {
      const float yc = (p == 0) ? sq4.x : (p == 1) ? sq4.y
                      : (p == 2) ? sq4.z : sq4.w;
      const float ic = (p == 0) ? iv4.x : (p == 1) ? iv4.y
                      : (p == 2) ? iv4.z : iv4.w;
      const float diff = fmaxf(xsq_i + yc - 2.0f * acc[p], 0.0f);
      zt[p] = fmaf(diff * inv2_i, ic, 1.0f);
    }
    if (jb == i0w) {   // wave-uniform diagonal tile
#pragma unroll
      for (int p = 0; p < 4; ++p)
        if (gi == jb + lk4 + p) zt[p] = INF_;
    }
    const float zm = fminf(fminf(zt[0], zt[1]), fminf(zt[2], zt[3]));
    if (zm <= tau_) {
#pragma unroll
      for (int p = 0; p < 4; ++p) {
        uint64_t key = ((uint64_t)__float_as_uint(zt[p]) << 32) |
                       (uint32_t)(jb + lk4 + p);
        if (key < t5[TOPK - 1]) {
#pragma unroll
          for (int tt = 0; tt < TOPK; ++tt) {
            const uint64_t cv = t5[tt];
            if (key < cv) { t5[tt] = key; key = cv; }
          }
        }
      }
    }

    if (have_next)
      *(uint4*)(((T & 1) ? y0 : y1) + sr * YSTRIDE + sc8) = stg;
    __syncthreads();
  }

  // merge: row lc has 4 lists (lanes lk*16+lc).  mbuf aliases smem.
  uint64_t* mb = (uint64_t*)smem;     // [4][16][21]
#pragma unroll
  for (int t = 0; t < TOPK; ++t)
    mb[((size_t)(wid * 16) + lc) * 21 + lk * TOPK + t] = t5[t];
  __syncthreads();

  if (l < 16) {
    uint64_t cur[TOPK];
#pragma unroll
    for (int t = 0; t < TOPK; ++t) cur[t] = mb[((size_t)(wid * 16) + l) * 21 + t];
    for (int c = 1; c < 4; ++c) {
      for (int t = 0; t < TOPK; ++t) {
        uint64_t key = mb[((size_t)(wid * 16) + l) * 21 + c * TOPK + t];
        if (key >= cur[TOPK - 1]) break;   // lists sorted ascending
#pragma unroll
        for (int u = 0; u < TOPK; ++u) {
          const uint64_t cv = cur[u];
          if (key < cv) { cur[u] = key; key = cv; }
        }
      }
    }
#pragma unroll
    for (int t = 0; t < TOPK; ++t)
      partial[((size_t)(m * NQ + qq) * N + i0w + l) * TOPK + t] = cur[t];
  }
}

// K2: merge slab-partials -> top5; exact f32 pos_term recompute;
// threefry sampling + exact negative distances + logsumexp.
__global__ __launch_bounds__(64) void k_neg(const float* __restrict__ Xa,
                                            const float* __restrict__ Xt,
                                            const float* __restrict__ ysq,
                                            const float* __restrict__ inv,
                                            const uint64_t* __restrict__ partial,
                                            float* __restrict__ rowres) {
  const int m = blockIdx.y;
  const int i = blockIdx.x;
  const float* __restrict__ X = (m == 0) ? Xt : Xa;
  const uint32_t seed = (m == 0) ? 1u : 2u;  // key(1)=text, key(2)=audio
  const int lane = threadIdx.x;

  __shared__ float4 xi4[DIM / 4];
  __shared__ float posv[TOPK];
  if (lane < DIM / 4) xi4[lane] = ((const float4*)(X + (size_t)i * DIM))[lane];
  __syncthreads();

  // merge NQ sorted lists (uniform across lanes)
  uint64_t cur[TOPK];
#pragma unroll
  for (int t = 0; t < TOPK; ++t)
    cur[t] = partial[((size_t)(m * NQ) * N + i) * TOPK + t];
  for (int q = 1; q < NQ; ++q) {
    for (int t = 0; t < TOPK; ++t) {
      uint64_t key = partial[((size_t)(m * NQ + q) * N + i) * TOPK + t];
      if (key >= cur[TOPK - 1]) break;
#pragma unroll
      for (int u = 0; u < TOPK; ++u) {
        const uint64_t cv = cur[u];
        if (key < cv) { cur[u] = key; key = cv; }
      }
    }
  }

  const float ysq_i = ysq[m * N + i];
  const float inv_i = inv[m * N + i];

  // lanes 32..36: exact f32 distance for the 5 selected positives
  if (lane >= 32 && lane < 32 + TOPK) {
    const int t = lane - 32;
    const uint32_t c = (uint32_t)(cur[t] & 0xffffffffu);
    const float4* xc = (const float4*)(X + (size_t)c * DIM);
    float dot = 0.0f;
#pragma unroll
    for (int k = 0; k < DIM / 4; ++k) {
      const float4 a = xi4[k];
      const float4 b = xc[k];
      dot = fmaf(a.x, b.x, dot); dot = fmaf(a.y, b.y, dot);
      dot = fmaf(a.z, b.z, dot); dot = fmaf(a.w, b.w, dot);
    }
    const float diff = fmaxf(ysq_i + ysq[m * N + c] - 2.0f * dot, 0.0f);
    const float z = 1.0f + 2.0f * diff * inv_i * inv[m * N + c];
    posv[t] = -acosh_dev(z) / TAU_;
  }

  uint32_t pidx[TOPK];
#pragma unroll
  for (int t = 0; t < TOPK; ++t) pidx[t] = (uint32_t)(cur[t] & 0xffffffffu);

#define CSWAP(a, b)                                                           \
  { const uint32_t mn = pidx[a] < pidx[b] ? pidx[a] : pidx[b];                \
    const uint32_t mx = pidx[a] < pidx[b] ? pidx[b] : pidx[a];                \
    pidx[a] = mn; pidx[b] = mx; }
  CSWAP(0, 1) CSWAP(3, 4) CSWAP(2, 4) CSWAP(2, 3) CSWAP(1, 4)
  CSWAP(0, 3) CSWAP(0, 2) CSWAP(1, 3) CSWAP(1, 2)
#undef CSWAP

  float v = -1e30f;
  if (lane < NEGS) {
    const uint32_t f = (uint32_t)i * (uint32_t)NEGS + (uint32_t)lane;
    uint32_t c = sample_idx(seed, f);
#pragma unroll
    for (int t = 0; t < TOPK; ++t) c += (c >= pidx[t]) ? 1u : 0u;
    if (c != (uint32_t)i) {
      const float4* xc = (const float4*)(X + (size_t)c * DIM);
      float dot = 0.0f;
#pragma unroll
      for (int k = 0; k < DIM / 4; ++k) {
        const float4 a = xi4[k];
        const float4 b = xc[k];
        dot = fmaf(a.x, b.x, dot); dot = fmaf(a.y, b.y, dot);
        dot = fmaf(a.z, b.z, dot); dot = fmaf(a.w, b.w, dot);
      }
      const float diff = fmaxf(ysq_i + ysq[m * N + c] - 2.0f * dot, 0.0f);
      const float z = 1.0f + 2.0f * diff * inv_i * inv[m * N + c];
      v = -acosh_dev(z) / TAU_;
    }
  }

  __syncthreads();   // posv visible

  float vmax = v;
#pragma unroll
  for (int o = 32; o > 0; o >>= 1) vmax = fmaxf(vmax, __shfl_xor(vmax, o, 64));
  float e = expf(v - vmax);
  float ss = e;
#pragma unroll
  for (int o = 32; o > 0; o >>= 1) ss += __shfl_xor(ss, o, 64);

  if (lane == 0) {
    float vm = -1e30f;
#pragma unroll
    for (int t = 0; t < TOPK; ++t) vm = fmaxf(vm, posv[t]);
    float ps = 0.0f;
#pragma unroll
    for (int t = 0; t < TOPK; ++t) ps += expf(posv[t] - vm);
    const float pos = vm + logf(ps);
    rowres[m * N + i] = (vmax + logf(ss)) - pos;
  }
}

// K3: deterministic final reduce (f64 accumulation), out = 0.01 * mean
__global__ __launch_bounds__(256) void k_reduce(const float* __restrict__ rowres,
                                                float* __restrict__ out) {
  __shared__ double sh[256];
  double s = 0.0;
  for (int idx = threadIdx.x; idx < 2 * N; idx += 256) s += (double)rowres[idx];
  sh[threadIdx.x] = s;
  __syncthreads();
  for (int o = 128; o > 0; o >>= 1) {
    if (threadIdx.x < o) sh[threadIdx.x] += sh[threadIdx.x + o];
    __syncthreads();
  }
  if (threadIdx.x == 0) out[0] = (float)(0.01 * (sh[0] / (double)N));
}

extern "C" void kernel_launch(void* const* d_in, const int* in_sizes, int n_in,
                              void* d_out, int out_size, void* d_ws,
                              size_t ws_size, hipStream_t stream) {
  const float* Xa = (const float*)d_in[0];   // audio_embeds
  const float* Xt = (const float*)d_in[1];   // text_embeds
  float* out = (float*)d_out;

  // ws layout (~7.4 MB): ysq[2N] | inv[2N] | partial[2*NQ*N*5 u64] | rowres[2N]
  //                      | Xs[2*N*128 u16]
  float* ysq = (float*)d_ws;
  float* inv = ysq + 2 * N;
  uint64_t* partial = (uint64_t*)(inv + 2 * N);
  float* rowres = (float*)(partial + (size_t)2 * NQ * N * TOPK);
  uint16_t* Xs = (uint16_t*)(rowres + 2 * N);

  k_pre<<<dim3(N / 64, 2), 64, 0, stream>>>(Xa, Xt, Xs, ysq, inv);
  k_top5<<<(N / RPB) * NQ * 2, 256, 0, stream>>>(Xs, ysq, inv, partial);
  k_neg<<<dim3(N, 2), 64, 0, stream>>>(Xa, Xt, ysq, inv, partial, rowres);
  k_reduce<<<1, 256, 0, stream>>>(rowres, out);
}

// Round 10
// 104.824 us; speedup vs baseline: 1.2657x; 1.0218x over previous
//
#include <hip/hip_runtime.h>
#include <stdint.h>

#define JAX_PARTITIONABLE 1

constexpr int N = 4096;
constexpr int DIM = 64;
constexpr int TOPK = 5;
constexpr int NEGS = 20;
constexpr float TAU_ = 0.1f;
constexpr uint32_t SPAN = 4091u;   // N - TOPK
constexpr uint32_t MULT = 2309u;   // ((1<<16) % SPAN)^2 % SPAN

constexpr int CQ = 256;            // cols per block slab
constexpr int NQ = N / CQ;         // 16 col groups
constexpr int NT = CQ / 16;        // 16 tiles per slab
constexpr int RPB = 64;            // rows per block (4 waves x 16)
constexpr int YSTRIDE = 136;       // padded LDS row stride in u16 (272 B)

typedef __attribute__((ext_vector_type(8))) short bf16x8;
typedef __attribute__((ext_vector_type(4))) float f32x4;

__device__ __forceinline__ uint32_t rotl32(uint32_t v, int d) {
  return (v << d) | (v >> (32 - d));
}

// Threefry-2x32, 20 rounds, exactly as jax/_src/prng.py lowering.
__device__ __forceinline__ void threefry(uint32_t k0, uint32_t k1,
                                         uint32_t& x0, uint32_t& x1) {
  const uint32_t k2 = k0 ^ k1 ^ 0x1BD11BDAu;
  x0 += k0; x1 += k1;
#define TF_R(r) { x0 += x1; x1 = rotl32(x1, r); x1 ^= x0; }
  TF_R(13) TF_R(15) TF_R(26) TF_R(6)
  x0 += k1; x1 += k2 + 1u;
  TF_R(17) TF_R(29) TF_R(16) TF_R(24)
  x0 += k2; x1 += k0 + 2u;
  TF_R(13) TF_R(15) TF_R(26) TF_R(6)
  x0 += k0; x1 += k1 + 3u;
  TF_R(17) TF_R(29) TF_R(16) TF_R(24)
  x0 += k1; x1 += k2 + 4u;
  TF_R(13) TF_R(15) TF_R(26) TF_R(6)
  x0 += k2; x1 += k0 + 5u;
#undef TF_R
}

__device__ __forceinline__ uint32_t sample_idx(uint32_t seed, uint32_t f) {
#if JAX_PARTITIONABLE
  uint32_t a0 = 0u, a1 = 0u; threefry(0u, seed, a0, a1);   // k1 = enc(key,(0,0))
  uint32_t b0 = 0u, b1 = 1u; threefry(0u, seed, b0, b1);   // k2 = enc(key,(0,1))
  uint32_t h0 = 0u, h1 = f;  threefry(a0, a1, h0, h1);
  const uint32_t hi = h0 ^ h1;
  uint32_t l0 = 0u, l1 = f;  threefry(b0, b1, l0, l1);
  const uint32_t lo = l0 ^ l1;
#else
  uint32_t a0 = 0u, a1 = 2u; threefry(0u, seed, a0, a1);
  uint32_t c0 = 1u, c1 = 3u; threefry(0u, seed, c0, c1);
  const uint32_t HALF = (uint32_t)(N * NEGS / 2);
  uint32_t hi, lo;
  if (f < HALF) {
    uint32_t x0 = f, x1 = f + HALF; threefry(a0, c0, x0, x1); hi = x0;
    x0 = f; x1 = f + HALF;          threefry(a1, c1, x0, x1); lo = x0;
  } else {
    uint32_t x0 = f - HALF, x1 = f; threefry(a0, c0, x0, x1); hi = x1;
    x0 = f - HALF; x1 = f;          threefry(a1, c1, x0, x1); lo = x1;
  }
#endif
  return ((hi % SPAN) * MULT + (lo % SPAN)) % SPAN;
}

__device__ __forceinline__ float acosh_dev(float z) {
  return logf(z + sqrtf((z - 1.0f) * (z + 1.0f)));
}

__device__ __forceinline__ uint16_t f2bf(float f) {   // RNE f32 -> bf16
  const uint32_t u = __float_as_uint(f);
  return (uint16_t)((u + 0x7FFFu + ((u >> 16) & 1u)) >> 16);
}
__device__ __forceinline__ float bf2f(uint16_t h) {
  return __uint_as_float((uint32_t)h << 16);
}

// K_pre: per row: exact f32 norms + inv, and bf16 hi/lo split rows
// Xs layout: [mod][row][128 u16] = hi[64] | lo[64], row stride 256 B.
__global__ __launch_bounds__(64) void k_pre(const float* __restrict__ Xa,
                                            const float* __restrict__ Xt,
                                            uint16_t* __restrict__ Xs,
                                            float* __restrict__ ysq,
                                            float* __restrict__ inv) {
  const int m = blockIdx.y;                  // 0 = text, 1 = audio
  const float* __restrict__ X = (m == 0) ? Xt : Xa;
  const int i = blockIdx.x * 64 + threadIdx.x;
  const float* xr = X + (size_t)i * DIM;

  uint32_t hb[DIM / 2], lb[DIM / 2];
  float s = 0.0f;
#pragma unroll
  for (int u = 0; u < DIM / 4; ++u) {
    const float4 v = *(const float4*)(xr + 4 * u);
    s = fmaf(v.x, v.x, s); s = fmaf(v.y, v.y, s);
    s = fmaf(v.z, v.z, s); s = fmaf(v.w, v.w, s);
    const uint16_t h0 = f2bf(v.x), h1 = f2bf(v.y), h2 = f2bf(v.z), h3 = f2bf(v.w);
    const uint16_t l0 = f2bf(v.x - bf2f(h0)), l1 = f2bf(v.y - bf2f(h1));
    const uint16_t l2 = f2bf(v.z - bf2f(h2)), l3 = f2bf(v.w - bf2f(h3));
    hb[2 * u]     = (uint32_t)h0 | ((uint32_t)h1 << 16);
    hb[2 * u + 1] = (uint32_t)h2 | ((uint32_t)h3 << 16);
    lb[2 * u]     = (uint32_t)l0 | ((uint32_t)l1 << 16);
    lb[2 * u + 1] = (uint32_t)l2 | ((uint32_t)l3 << 16);
  }
  uint32_t* dst = (uint32_t*)(Xs + (size_t)(m * N + i) * 128);
#pragma unroll
  for (int w = 0; w < 8; ++w) {
    uint4 qh = { hb[4 * w], hb[4 * w + 1], hb[4 * w + 2], hb[4 * w + 3] };
    ((uint4*)dst)[w] = qh;
  }
#pragma unroll
  for (int w = 0; w < 8; ++w) {
    uint4 ql = { lb[4 * w], lb[4 * w + 1], lb[4 * w + 2], lb[4 * w + 3] };
    ((uint4*)dst)[8 + w] = ql;
  }
  ysq[m * N + i] = s;
  inv[m * N + i] = 1.0f / (1.0f - fminf(s, 1.0f));
}

// K1: MFMA pairwise-z + per-row top-5 partials.
// 4-wave block: 64 rows x 256-col slab. Y tiles staged cooperatively in LDS,
// 4-buffer rotation, ONE barrier per 2 tiles (8/block). Screen = lane's own
// 5th-best (no cross-lane bpermute — round-8's tau screen cost ~200cyc/tile
// on the DS pipe and produced the 2.1M bank-conflict count).
__global__ __launch_bounds__(256) void k_top5(
    const uint16_t* __restrict__ Xs, const float* __restrict__ ysq,
    const float* __restrict__ inv, uint64_t* __restrict__ partial) {
  // bijective XCD swizzle over 2048 blocks (2048 % 8 == 0)
  const int lin = (int)blockIdx.x;
  const int wg = ((lin & 7) << 8) | (lin >> 3);
  const int m = wg >> 10;               // 2
  const int qq = (wg >> 6) & 15;        // 16 col slabs
  const int rb = wg & 63;               // 64 row blocks

  const int tid = (int)threadIdx.x;
  const int wid = tid >> 6;
  const int l = tid & 63;
  const int i0w = rb * RPB + wid * 16;  // this wave's 16 rows
  const int j0q = qq * CQ;
  const int mN = m * N;
  const uint16_t* __restrict__ Xm = Xs + (size_t)m * N * 128;
  const int lc = l & 15;                // output row index within wave
  const int lk = l >> 4;
  const int lk4 = lk * 4;               // candidate-col base
  const int lk8 = lk * 8;               // u16 k-slice offset
  const int sr = tid >> 4;              // staging row (0..15)
  const int sc8 = (tid & 15) * 8;       // staging seg (u16 units, 16B)

  // LDS: 4 y-bufs (4x4352B) + sq/iv (2048B) = 19456B -> 8 blocks/CU.
  // merge mbuf [4][16][21] u64 (10752B) aliases the y-bufs afterwards.
  __shared__ __align__(16) unsigned char smem[4 * 16 * YSTRIDE * 2 + 2048];
  uint16_t* ybuf = (uint16_t*)smem;     // buf b at ybuf + b*16*YSTRIDE
  float* sq_s = (float*)(smem + 4 * 16 * YSTRIDE * 2);
  float* iv_s = sq_s + CQ;

  // A fragments (this wave's rows): xf[k-chunk][hi/lo]
  bf16x8 xf[2][2];
#pragma unroll
  for (int c = 0; c < 2; ++c)
#pragma unroll
    for (int h = 0; h < 2; ++h)
      xf[c][h] = *(const bf16x8*)(Xm + (size_t)(i0w + lc) * 128 +
                                  h * 64 + c * 32 + lk8);

  const float xsq_i = ysq[mN + i0w + lc];
  const float inv2_i = 2.0f * inv[mN + i0w + lc];
  const int gi = i0w + lc;

  const uint64_t SENT = ((uint64_t)0x7F800000u << 32) | 0xFFFFFFFFu;
  uint64_t t5[TOPK];
#pragma unroll
  for (int t = 0; t < TOPK; ++t) t5[t] = SENT;
  float z5own = __uint_as_float(0x7F800000u);   // +inf

  const f32x4 zz = {0.0f, 0.0f, 0.0f, 0.0f};
  const float INF_ = __uint_as_float(0x7F800000u);

  {  // prologue: stage sq/iv slab + tiles 0,1
    if (tid < 64)
      *(float4*)&sq_s[tid * 4] = *(const float4*)&ysq[mN + j0q + tid * 4];
    else if (tid < 128)
      *(float4*)&iv_s[(tid - 64) * 4] =
          *(const float4*)&inv[mN + j0q + (tid - 64) * 4];
    *(uint4*)(ybuf + sr * YSTRIDE + sc8) =
        *(const uint4*)(Xm + (size_t)(j0q + sr) * 128 + sc8);
    *(uint4*)(ybuf + 16 * YSTRIDE + sr * YSTRIDE + sc8) =
        *(const uint4*)(Xm + (size_t)(j0q + 16 + sr) * 128 + sc8);
    __syncthreads();
  }

#define PROCESS(T, BUF)                                                        \
  {                                                                            \
    const uint16_t* yp = (BUF) + lc * YSTRIDE + lk8;                           \
    const bf16x8 Y0 = *(const bf16x8*)(yp);                                    \
    const bf16x8 Y1 = *(const bf16x8*)(yp + 32);                               \
    const bf16x8 Y2 = *(const bf16x8*)(yp + 64);                               \
    const bf16x8 Y3 = *(const bf16x8*)(yp + 96);                               \
    f32x4 acc;  /* same term order as rounds 3-8 (bit-exact z) */              \
    acc = __builtin_amdgcn_mfma_f32_16x16x32_bf16(Y0, xf[0][0], zz, 0, 0, 0);  \
    acc = __builtin_amdgcn_mfma_f32_16x16x32_bf16(Y1, xf[1][0], acc, 0, 0, 0); \
    acc = __builtin_amdgcn_mfma_f32_16x16x32_bf16(Y2, xf[0][0], acc, 0, 0, 0); \
    acc = __builtin_amdgcn_mfma_f32_16x16x32_bf16(Y3, xf[1][0], acc, 0, 0, 0); \
    acc = __builtin_amdgcn_mfma_f32_16x16x32_bf16(Y0, xf[0][1], acc, 0, 0, 0); \
    acc = __builtin_amdgcn_mfma_f32_16x16x32_bf16(Y1, xf[1][1], acc, 0, 0, 0); \
    const float4 sq4 = *(const float4*)&sq_s[(T) * 16 + lk4];                  \
    const float4 iv4 = *(const float4*)&iv_s[(T) * 16 + lk4];                  \
    const int jb = j0q + (T) * 16;                                             \
    float zt[4];                                                               \
    _Pragma("unroll") for (int p = 0; p < 4; ++p) {                            \
      const float yc = (p == 0) ? sq4.x : (p == 1) ? sq4.y                     \
                      : (p == 2) ? sq4.z : sq4.w;                              \
      const float ic = (p == 0) ? iv4.x : (p == 1) ? iv4.y                     \
                      : (p == 2) ? iv4.z : iv4.w;                              \
      const float diff = fmaxf(xsq_i + yc - 2.0f * acc[p], 0.0f);              \
      zt[p] = fmaf(diff * inv2_i, ic, 1.0f);                                   \
    }                                                                          \
    if (jb == i0w) {   /* wave-uniform diagonal tile */                        \
      _Pragma("unroll") for (int p = 0; p < 4; ++p)                            \
        if (gi == jb + lk4 + p) zt[p] = INF_;                                  \
    }                                                                          \
    const float zm = fminf(fminf(zt[0], zt[1]), fminf(zt[2], zt[3]));          \
    if (zm <= z5own) {                                                         \
      _Pragma("unroll") for (int p = 0; p < 4; ++p) {                          \
        uint64_t key = ((uint64_t)__float_as_uint(zt[p]) << 32) |              \
                       (uint32_t)(jb + lk4 + p);                               \
        if (key < t5[TOPK - 1]) {                                              \
          _Pragma("unroll") for (int tt = 0; tt < TOPK; ++tt) {                \
            const uint64_t cv = t5[tt];                                        \
            if (key < cv) { t5[tt] = key; key = cv; }                          \
          }                                                                    \
        }                                                                      \
      }                                                                        \
      z5own = __uint_as_float((uint32_t)(t5[TOPK - 1] >> 32));                 \
    }                                                                          \
  }

#pragma unroll 1
  for (int T = 0; T < NT; T += 2) {
    const bool hn = (T + 2 < NT);
    uint4 s2, s3;
    if (hn) {   // issue next-pair global loads early (T14 split)
      s2 = *(const uint4*)(Xm + (size_t)(j0q + (T + 2) * 16 + sr) * 128 + sc8);
      s3 = *(const uint4*)(Xm + (size_t)(j0q + (T + 3) * 16 + sr) * 128 + sc8);
    }
    PROCESS(T, ybuf + (size_t)((T) & 3) * 16 * YSTRIDE)
    PROCESS(T + 1, ybuf + (size_t)((T + 1) & 3) * 16 * YSTRIDE)
    if (hn) {
      *(uint4*)(ybuf + (size_t)((T + 2) & 3) * 16 * YSTRIDE + sr * YSTRIDE + sc8) = s2;
      *(uint4*)(ybuf + (size_t)((T + 3) & 3) * 16 * YSTRIDE + sr * YSTRIDE + sc8) = s3;
    }
    __syncthreads();
  }
#undef PROCESS

  // merge: row lc has 4 lists (lanes lk*16+lc).  mbuf aliases smem.
  uint64_t* mb = (uint64_t*)smem;     // [4][16][21]
#pragma unroll
  for (int t = 0; t < TOPK; ++t)
    mb[((size_t)(wid * 16) + lc) * 21 + lk * TOPK + t] = t5[t];
  __syncthreads();

  if (l < 16) {
    uint64_t cur[TOPK];
#pragma unroll
    for (int t = 0; t < TOPK; ++t) cur[t] = mb[((size_t)(wid * 16) + l) * 21 + t];
    for (int c = 1; c < 4; ++c) {
      for (int t = 0; t < TOPK; ++t) {
        uint64_t key = mb[((size_t)(wid * 16) + l) * 21 + c * TOPK + t];
        if (key >= cur[TOPK - 1]) break;   // lists sorted ascending
#pragma unroll
        for (int u = 0; u < TOPK; ++u) {
          const uint64_t cv = cur[u];
          if (key < cv) { cur[u] = key; key = cv; }
        }
      }
    }
#pragma unroll
    for (int t = 0; t < TOPK; ++t)
      partial[((size_t)(m * NQ + qq) * N + i0w + l) * TOPK + t] = cur[t];
  }
}

// K2: merge slab-partials -> top5; exact f32 pos_term recompute;
// threefry sampling + exact negative distances + logsumexp.
__global__ __launch_bounds__(64) void k_neg(const float* __restrict__ Xa,
                                            const float* __restrict__ Xt,
                                            const float* __restrict__ ysq,
                                            const float* __restrict__ inv,
                                            const uint64_t* __restrict__ partial,
                                            float* __restrict__ rowres) {
  const int m = blockIdx.y;
  const int i = blockIdx.x;
  const float* __restrict__ X = (m == 0) ? Xt : Xa;
  const uint32_t seed = (m == 0) ? 1u : 2u;  // key(1)=text, key(2)=audio
  const int lane = threadIdx.x;

  __shared__ float4 xi4[DIM / 4];
  __shared__ float posv[TOPK];
  if (lane < DIM / 4) xi4[lane] = ((const float4*)(X + (size_t)i * DIM))[lane];
  __syncthreads();

  // merge NQ sorted lists (uniform across lanes)
  uint64_t cur[TOPK];
#pragma unroll
  for (int t = 0; t < TOPK; ++t)
    cur[t] = partial[((size_t)(m * NQ) * N + i) * TOPK + t];
  for (int q = 1; q < NQ; ++q) {
    for (int t = 0; t < TOPK; ++t) {
      uint64_t key = partial[((size_t)(m * NQ + q) * N + i) * TOPK + t];
      if (key >= cur[TOPK - 1]) break;
#pragma unroll
      for (int u = 0; u < TOPK; ++u) {
        const uint64_t cv = cur[u];
        if (key < cv) { cur[u] = key; key = cv; }
      }
    }
  }

  const float ysq_i = ysq[m * N + i];
  const float inv_i = inv[m * N + i];

  // lanes 32..36: exact f32 distance for the 5 selected positives
  if (lane >= 32 && lane < 32 + TOPK) {
    const int t = lane - 32;
    const uint32_t c = (uint32_t)(cur[t] & 0xffffffffu);
    const float4* xc = (const float4*)(X + (size_t)c * DIM);
    float dot = 0.0f;
#pragma unroll
    for (int k = 0; k < DIM / 4; ++k) {
      const float4 a = xi4[k];
      const float4 b = xc[k];
      dot = fmaf(a.x, b.x, dot); dot = fmaf(a.y, b.y, dot);
      dot = fmaf(a.z, b.z, dot); dot = fmaf(a.w, b.w, dot);
    }
    const float diff = fmaxf(ysq_i + ysq[m * N + c] - 2.0f * dot, 0.0f);
    const float z = 1.0f + 2.0f * diff * inv_i * inv[m * N + c];
    posv[t] = -acosh_dev(z) / TAU_;
  }

  uint32_t pidx[TOPK];
#pragma unroll
  for (int t = 0; t < TOPK; ++t) pidx[t] = (uint32_t)(cur[t] & 0xffffffffu);

#define CSWAP(a, b)                                                           \
  { const uint32_t mn = pidx[a] < pidx[b] ? pidx[a] : pidx[b];                \
    const uint32_t mx = pidx[a] < pidx[b] ? pidx[b] : pidx[a];                \
    pidx[a] = mn; pidx[b] = mx; }
  CSWAP(0, 1) CSWAP(3, 4) CSWAP(2, 4) CSWAP(2, 3) CSWAP(1, 4)
  CSWAP(0, 3) CSWAP(0, 2) CSWAP(1, 3) CSWAP(1, 2)
#undef CSWAP

  float v = -1e30f;
  if (lane < NEGS) {
    const uint32_t f = (uint32_t)i * (uint32_t)NEGS + (uint32_t)lane;
    uint32_t c = sample_idx(seed, f);
#pragma unroll
    for (int t = 0; t < TOPK; ++t) c += (c >= pidx[t]) ? 1u : 0u;
    if (c != (uint32_t)i) {
      const float4* xc = (const float4*)(X + (size_t)c * DIM);
      float dot = 0.0f;
#pragma unroll
      for (int k = 0; k < DIM / 4; ++k) {
        const float4 a = xi4[k];
        const float4 b = xc[k];
        dot = fmaf(a.x, b.x, dot); dot = fmaf(a.y, b.y, dot);
        dot = fmaf(a.z, b.z, dot); dot = fmaf(a.w, b.w, dot);
      }
      const float diff = fmaxf(ysq_i + ysq[m * N + c] - 2.0f * dot, 0.0f);
      const float z = 1.0f + 2.0f * diff * inv_i * inv[m * N + c];
      v = -acosh_dev(z) / TAU_;
    }
  }

  __syncthreads();   // posv visible

  float vmax = v;
#pragma unroll
  for (int o = 32; o > 0; o >>= 1) vmax = fmaxf(vmax, __shfl_xor(vmax, o, 64));
  float e = expf(v - vmax);
  float ss = e;
#pragma unroll
  for (int o = 32; o > 0; o >>= 1) ss += __shfl_xor(ss, o, 64);

  if (lane == 0) {
    float vm = -1e30f;
#pragma unroll
    for (int t = 0; t < TOPK; ++t) vm = fmaxf(vm, posv[t]);
    float ps = 0.0f;
#pragma unroll
    for (int t = 0; t < TOPK; ++t) ps += expf(posv[t] - vm);
    const float pos = vm + logf(ps);
    rowres[m * N + i] = (vmax + logf(ss)) - pos;
  }
}

// K3: deterministic final reduce (f64 accumulation), out = 0.01 * mean
__global__ __launch_bounds__(256) void k_reduce(const float* __restrict__ rowres,
                                                float* __restrict__ out) {
  __shared__ double sh[256];
  double s = 0.0;
  for (int idx = threadIdx.x; idx < 2 * N; idx += 256) s += (double)rowres[idx];
  sh[threadIdx.x] = s;
  __syncthreads();
  for (int o = 128; o > 0; o >>= 1) {
    if (threadIdx.x < o) sh[threadIdx.x] += sh[threadIdx.x + o];
    __syncthreads();
  }
  if (threadIdx.x == 0) out[0] = (float)(0.01 * (sh[0] / (double)N));
}

extern "C" void kernel_launch(void* const* d_in, const int* in_sizes, int n_in,
                              void* d_out, int out_size, void* d_ws,
                              size_t ws_size, hipStream_t stream) {
  const float* Xa = (const float*)d_in[0];   // audio_embeds
  const float* Xt = (const float*)d_in[1];   // text_embeds
  float* out = (float*)d_out;

  // ws layout (~7.4 MB): ysq[2N] | inv[2N] | partial[2*NQ*N*5 u64] | rowres[2N]
  //                      | Xs[2*N*128 u16]
  float* ysq = (float*)d_ws;
  float* inv = ysq + 2 * N;
  uint64_t* partial = (uint64_t*)(inv + 2 * N);
  float* rowres = (float*)(partial + (size_t)2 * NQ * N * TOPK);
  uint16_t* Xs = (uint16_t*)(rowres + 2 * N);

  k_pre<<<dim3(N / 64, 2), 64, 0, stream>>>(Xa, Xt, Xs, ysq, inv);
  k_top5<<<(N / RPB) * NQ * 2, 256, 0, stream>>>(Xs, ysq, inv, partial);
  k_neg<<<dim3(N, 2), 64, 0, stream>>>(Xa, Xt, ysq, inv, partial, rowres);
  k_reduce<<<1, 256, 0, stream>>>(rowres, out);
}

// Round 11
// 99.905 us; speedup vs baseline: 1.3280x; 1.0492x over previous
//
#include <hip/hip_runtime.h>
#include <stdint.h>

#define JAX_PARTITIONABLE 1

constexpr int N = 4096;
constexpr int DIM = 64;
constexpr int TOPK = 5;
constexpr int NEGS = 20;
constexpr float TAU_ = 0.1f;
constexpr uint32_t SPAN = 4091u;   // N - TOPK
constexpr uint32_t MULT = 2309u;   // ((1<<16) % SPAN)^2 % SPAN

constexpr int CQ = 256;            // cols per block slab
constexpr int NT = CQ / 16;        // 16 tiles per slab
constexpr int RPB = 64;            // rows per block (4 waves x 16)
constexpr int YSTRIDE = 136;       // padded LDS row stride in u16 (272 B)
constexpr int NQB = 4;             // bound-phase slabs (own quarter)
constexpr int CAP = 64;            // survivor list capacity per row

typedef __attribute__((ext_vector_type(8))) short bf16x8;
typedef __attribute__((ext_vector_type(4))) float f32x4;

__device__ __forceinline__ uint32_t rotl32(uint32_t v, int d) {
  return (v << d) | (v >> (32 - d));
}

// Threefry-2x32, 20 rounds, exactly as jax/_src/prng.py lowering.
__device__ __forceinline__ void threefry(uint32_t k0, uint32_t k1,
                                         uint32_t& x0, uint32_t& x1) {
  const uint32_t k2 = k0 ^ k1 ^ 0x1BD11BDAu;
  x0 += k0; x1 += k1;
#define TF_R(r) { x0 += x1; x1 = rotl32(x1, r); x1 ^= x0; }
  TF_R(13) TF_R(15) TF_R(26) TF_R(6)
  x0 += k1; x1 += k2 + 1u;
  TF_R(17) TF_R(29) TF_R(16) TF_R(24)
  x0 += k2; x1 += k0 + 2u;
  TF_R(13) TF_R(15) TF_R(26) TF_R(6)
  x0 += k0; x1 += k1 + 3u;
  TF_R(17) TF_R(29) TF_R(16) TF_R(24)
  x0 += k1; x1 += k2 + 4u;
  TF_R(13) TF_R(15) TF_R(26) TF_R(6)
  x0 += k2; x1 += k0 + 5u;
#undef TF_R
}

__device__ __forceinline__ uint32_t sample_idx(uint32_t seed, uint32_t f) {
#if JAX_PARTITIONABLE
  uint32_t a0 = 0u, a1 = 0u; threefry(0u, seed, a0, a1);   // k1 = enc(key,(0,0))
  uint32_t b0 = 0u, b1 = 1u; threefry(0u, seed, b0, b1);   // k2 = enc(key,(0,1))
  uint32_t h0 = 0u, h1 = f;  threefry(a0, a1, h0, h1);
  const uint32_t hi = h0 ^ h1;
  uint32_t l0 = 0u, l1 = f;  threefry(b0, b1, l0, l1);
  const uint32_t lo = l0 ^ l1;
#else
  uint32_t a0 = 0u, a1 = 2u; threefry(0u, seed, a0, a1);
  uint32_t c0 = 1u, c1 = 3u; threefry(0u, seed, c0, c1);
  const uint32_t HALF = (uint32_t)(N * NEGS / 2);
  uint32_t hi, lo;
  if (f < HALF) {
    uint32_t x0 = f, x1 = f + HALF; threefry(a0, c0, x0, x1); hi = x0;
    x0 = f; x1 = f + HALF;          threefry(a1, c1, x0, x1); lo = x0;
  } else {
    uint32_t x0 = f - HALF, x1 = f; threefry(a0, c0, x0, x1); hi = x1;
    x0 = f - HALF; x1 = f;          threefry(a1, c1, x0, x1); lo = x1;
  }
#endif
  return ((hi % SPAN) * MULT + (lo % SPAN)) % SPAN;
}

__device__ __forceinline__ float acosh_dev(float z) {
  return logf(z + sqrtf((z - 1.0f) * (z + 1.0f)));
}

__device__ __forceinline__ uint16_t f2bf(float f) {   // RNE f32 -> bf16
  const uint32_t u = __float_as_uint(f);
  return (uint16_t)((u + 0x7FFFu + ((u >> 16) & 1u)) >> 16);
}
__device__ __forceinline__ float bf2f(uint16_t h) {
  return __uint_as_float((uint32_t)h << 16);
}

// K_pre: per row: exact f32 norms + inv, bf16 hi/lo split rows, zero cnt.
// Xs layout: [mod][row][128 u16] = hi[64] | lo[64], row stride 256 B.
__global__ __launch_bounds__(64) void k_pre(const float* __restrict__ Xa,
                                            const float* __restrict__ Xt,
                                            uint16_t* __restrict__ Xs,
                                            float* __restrict__ ysq,
                                            float* __restrict__ inv,
                                            uint32_t* __restrict__ cnt) {
  const int m = blockIdx.y;                  // 0 = text, 1 = audio
  const float* __restrict__ X = (m == 0) ? Xt : Xa;
  const int i = blockIdx.x * 64 + threadIdx.x;
  const float* xr = X + (size_t)i * DIM;

  uint32_t hb[DIM / 2], lb[DIM / 2];
  float s = 0.0f;
#pragma unroll
  for (int u = 0; u < DIM / 4; ++u) {
    const float4 v = *(const float4*)(xr + 4 * u);
    s = fmaf(v.x, v.x, s); s = fmaf(v.y, v.y, s);
    s = fmaf(v.z, v.z, s); s = fmaf(v.w, v.w, s);
    const uint16_t h0 = f2bf(v.x), h1 = f2bf(v.y), h2 = f2bf(v.z), h3 = f2bf(v.w);
    const uint16_t l0 = f2bf(v.x - bf2f(h0)), l1 = f2bf(v.y - bf2f(h1));
    const uint16_t l2 = f2bf(v.z - bf2f(h2)), l3 = f2bf(v.w - bf2f(h3));
    hb[2 * u]     = (uint32_t)h0 | ((uint32_t)h1 << 16);
    hb[2 * u + 1] = (uint32_t)h2 | ((uint32_t)h3 << 16);
    lb[2 * u]     = (uint32_t)l0 | ((uint32_t)l1 << 16);
    lb[2 * u + 1] = (uint32_t)l2 | ((uint32_t)l3 << 16);
  }
  uint32_t* dst = (uint32_t*)(Xs + (size_t)(m * N + i) * 128);
#pragma unroll
  for (int w = 0; w < 8; ++w) {
    uint4 qh = { hb[4 * w], hb[4 * w + 1], hb[4 * w + 2], hb[4 * w + 3] };
    ((uint4*)dst)[w] = qh;
  }
#pragma unroll
  for (int w = 0; w < 8; ++w) {
    uint4 ql = { lb[4 * w], lb[4 * w + 1], lb[4 * w + 2], lb[4 * w + 3] };
    ((uint4*)dst)[8 + w] = ql;
  }
  ysq[m * N + i] = s;
  inv[m * N + i] = 1.0f / (1.0f - fminf(s, 1.0f));
  cnt[m * N + i] = 0u;   // survivor counter reset (graph-replay safe)
}

// K_bound: exact top-5 within each row's OWN QUARTER (4 slabs of 256 cols).
// Structure identical to round-9 k_top5 (insert-heavy path), restricted to
// the quarter so only 1/4 of tiles pay the u64 maintenance cost.
__global__ __launch_bounds__(256) void k_bound(
    const uint16_t* __restrict__ Xs, const float* __restrict__ ysq,
    const float* __restrict__ inv, uint64_t* __restrict__ partial) {
  const int rb = (int)blockIdx.x;       // 64 row blocks
  const int qs = (int)blockIdx.y;       // 4 slabs within own quarter
  const int m = (int)blockIdx.z;
  const int qr = rb >> 4;               // own quarter (0..3)
  const int j0q = (qr * NQB + qs) * CQ;

  const int tid = (int)threadIdx.x;
  const int wid = tid >> 6;
  const int l = tid & 63;
  const int i0w = rb * RPB + wid * 16;
  const int mN = m * N;
  const uint16_t* __restrict__ Xm = Xs + (size_t)m * N * 128;
  const int lc = l & 15;
  const int lk = l >> 4;
  const int lk4 = lk * 4;
  const int lk8 = lk * 8;
  const int sr = tid >> 4;
  const int sc8 = (tid & 15) * 8;

  __shared__ __align__(16) unsigned char smem[4 * 16 * YSTRIDE * 2 + 2048];
  uint16_t* ybuf = (uint16_t*)smem;
  float* sq_s = (float*)(smem + 4 * 16 * YSTRIDE * 2);
  float* iv_s = sq_s + CQ;

  bf16x8 xf[2][2];
#pragma unroll
  for (int c = 0; c < 2; ++c)
#pragma unroll
    for (int h = 0; h < 2; ++h)
      xf[c][h] = *(const bf16x8*)(Xm + (size_t)(i0w + lc) * 128 +
                                  h * 64 + c * 32 + lk8);

  const float xsq_i = ysq[mN + i0w + lc];
  const float inv2_i = 2.0f * inv[mN + i0w + lc];
  const int gi = i0w + lc;

  const uint64_t SENT = ((uint64_t)0x7F800000u << 32) | 0xFFFFFFFFu;
  uint64_t t5[TOPK];
#pragma unroll
  for (int t = 0; t < TOPK; ++t) t5[t] = SENT;
  float z5own = __uint_as_float(0x7F800000u);

  const f32x4 zz = {0.0f, 0.0f, 0.0f, 0.0f};
  const float INF_ = __uint_as_float(0x7F800000u);

  {  // prologue: stage sq/iv slab + tiles 0,1
    if (tid < 64)
      *(float4*)&sq_s[tid * 4] = *(const float4*)&ysq[mN + j0q + tid * 4];
    else if (tid < 128)
      *(float4*)&iv_s[(tid - 64) * 4] =
          *(const float4*)&inv[mN + j0q + (tid - 64) * 4];
    *(uint4*)(ybuf + sr * YSTRIDE + sc8) =
        *(const uint4*)(Xm + (size_t)(j0q + sr) * 128 + sc8);
    *(uint4*)(ybuf + 16 * YSTRIDE + sr * YSTRIDE + sc8) =
        *(const uint4*)(Xm + (size_t)(j0q + 16 + sr) * 128 + sc8);
    __syncthreads();
  }

#define PROCESS(T, BUF)                                                        \
  {                                                                            \
    const uint16_t* yp = (BUF) + lc * YSTRIDE + lk8;                           \
    const bf16x8 Y0 = *(const bf16x8*)(yp);                                    \
    const bf16x8 Y1 = *(const bf16x8*)(yp + 32);                               \
    const bf16x8 Y2 = *(const bf16x8*)(yp + 64);                               \
    const bf16x8 Y3 = *(const bf16x8*)(yp + 96);                               \
    f32x4 acc;  /* same term order as rounds 3-9 (bit-exact z) */              \
    acc = __builtin_amdgcn_mfma_f32_16x16x32_bf16(Y0, xf[0][0], zz, 0, 0, 0);  \
    acc = __builtin_amdgcn_mfma_f32_16x16x32_bf16(Y1, xf[1][0], acc, 0, 0, 0); \
    acc = __builtin_amdgcn_mfma_f32_16x16x32_bf16(Y2, xf[0][0], acc, 0, 0, 0); \
    acc = __builtin_amdgcn_mfma_f32_16x16x32_bf16(Y3, xf[1][0], acc, 0, 0, 0); \
    acc = __builtin_amdgcn_mfma_f32_16x16x32_bf16(Y0, xf[0][1], acc, 0, 0, 0); \
    acc = __builtin_amdgcn_mfma_f32_16x16x32_bf16(Y1, xf[1][1], acc, 0, 0, 0); \
    const float4 sq4 = *(const float4*)&sq_s[(T) * 16 + lk4];                  \
    const float4 iv4 = *(const float4*)&iv_s[(T) * 16 + lk4];                  \
    const int jb = j0q + (T) * 16;                                             \
    float zt[4];                                                               \
    _Pragma("unroll") for (int p = 0; p < 4; ++p) {                            \
      const float yc = (p == 0) ? sq4.x : (p == 1) ? sq4.y                     \
                      : (p == 2) ? sq4.z : sq4.w;                              \
      const float ic = (p == 0) ? iv4.x : (p == 1) ? iv4.y                     \
                      : (p == 2) ? iv4.z : iv4.w;                              \
      const float diff = fmaxf(xsq_i + yc - 2.0f * acc[p], 0.0f);              \
      zt[p] = fmaf(diff * inv2_i, ic, 1.0f);                                   \
    }                                                                          \
    if (jb == i0w) {                                                           \
      _Pragma("unroll") for (int p = 0; p < 4; ++p)                            \
        if (gi == jb + lk4 + p) zt[p] = INF_;                                  \
    }                                                                          \
    const float zm = fminf(fminf(zt[0], zt[1]), fminf(zt[2], zt[3]));          \
    if (zm <= z5own) {                                                         \
      _Pragma("unroll") for (int p = 0; p < 4; ++p) {                          \
        uint64_t key = ((uint64_t)__float_as_uint(zt[p]) << 32) |              \
                       (uint32_t)(jb + lk4 + p);                               \
        if (key < t5[TOPK - 1]) {                                              \
          _Pragma("unroll") for (int tt = 0; tt < TOPK; ++tt) {                \
            const uint64_t cv = t5[tt];                                        \
            if (key < cv) { t5[tt] = key; key = cv; }                          \
          }                                                                    \
        }                                                                      \
      }                                                                        \
      z5own = __uint_as_float((uint32_t)(t5[TOPK - 1] >> 32));                 \
    }                                                                          \
  }

#pragma unroll 1
  for (int T = 0; T < NT; T += 2) {
    const bool hn = (T + 2 < NT);
    uint4 s2, s3;
    if (hn) {
      s2 = *(const uint4*)(Xm + (size_t)(j0q + (T + 2) * 16 + sr) * 128 + sc8);
      s3 = *(const uint4*)(Xm + (size_t)(j0q + (T + 3) * 16 + sr) * 128 + sc8);
    }
    PROCESS(T, ybuf + (size_t)((T) & 3) * 16 * YSTRIDE)
    PROCESS(T + 1, ybuf + (size_t)((T + 1) & 3) * 16 * YSTRIDE)
    if (hn) {
      *(uint4*)(ybuf + (size_t)((T + 2) & 3) * 16 * YSTRIDE + sr * YSTRIDE + sc8) = s2;
      *(uint4*)(ybuf + (size_t)((T + 3) & 3) * 16 * YSTRIDE + sr * YSTRIDE + sc8) = s3;
    }
    __syncthreads();
  }
#undef PROCESS

  // merge: row lc has 4 lists (lanes lk*16+lc).  mbuf aliases smem.
  uint64_t* mb = (uint64_t*)smem;     // [4][16][21]
#pragma unroll
  for (int t = 0; t < TOPK; ++t)
    mb[((size_t)(wid * 16) + lc) * 21 + lk * TOPK + t] = t5[t];
  __syncthreads();

  if (l < 16) {
    uint64_t cur[TOPK];
#pragma unroll
    for (int t = 0; t < TOPK; ++t) cur[t] = mb[((size_t)(wid * 16) + l) * 21 + t];
    for (int c = 1; c < 4; ++c) {
      for (int t = 0; t < TOPK; ++t) {
        uint64_t key = mb[((size_t)(wid * 16) + l) * 21 + c * TOPK + t];
        if (key >= cur[TOPK - 1]) break;
#pragma unroll
        for (int u = 0; u < TOPK; ++u) {
          const uint64_t cv = cur[u];
          if (key < cv) { cur[u] = key; key = cv; }
        }
      }
    }
#pragma unroll
    for (int t = 0; t < TOPK; ++t)
      partial[((size_t)(m * NQB + qs) * N + i0w + l) * TOPK + t] = cur[t];
  }
}

// K_scan: the other 12 slabs, NO top-5 maintenance — exact screen vs the
// quarter bound B (merged from the 4 quarter partials); survivors (key < B)
// are appended to a per-row global list via atomicAdd. Exact: every true
// top-5 key outside the quarter satisfies key < B.
__global__ __launch_bounds__(256) void k_scan(
    const uint16_t* __restrict__ Xs, const float* __restrict__ ysq,
    const float* __restrict__ inv, const uint64_t* __restrict__ partial,
    uint32_t* __restrict__ cnt, uint64_t* __restrict__ rowlist) {
  const int rb = (int)blockIdx.x;       // 64 row blocks
  const int s = (int)blockIdx.y;        // 12 non-own slabs
  const int m = (int)blockIdx.z;
  const int qr = rb >> 4;
  const int gs = (s < qr * NQB) ? s : s + NQB;   // skip own quarter's slabs
  const int j0q = gs * CQ;

  const int tid = (int)threadIdx.x;
  const int wid = tid >> 6;
  const int l = tid & 63;
  const int i0w = rb * RPB + wid * 16;
  const int mN = m * N;
  const uint16_t* __restrict__ Xm = Xs + (size_t)m * N * 128;
  const int lc = l & 15;
  const int lk = l >> 4;
  const int lk4 = lk * 4;
  const int lk8 = lk * 8;
  const int sr = tid >> 4;
  const int sc8 = (tid & 15) * 8;
  const int gi = i0w + lc;              // this lane's row

  __shared__ __align__(16) unsigned char smem[4 * 16 * YSTRIDE * 2 + 2048];
  uint16_t* ybuf = (uint16_t*)smem;
  float* sq_s = (float*)(smem + 4 * 16 * YSTRIDE * 2);
  float* iv_s = sq_s + CQ;

  bf16x8 xf[2][2];
#pragma unroll
  for (int c = 0; c < 2; ++c)
#pragma unroll
    for (int h = 0; h < 2; ++h)
      xf[c][h] = *(const bf16x8*)(Xm + (size_t)gi * 128 + h * 64 + c * 32 + lk8);

  const float xsq_i = ysq[mN + gi];
  const float inv2_i = 2.0f * inv[mN + gi];

  // bound = 5th-smallest key of the row's own quarter (merge 4 sorted lists;
  // the 4 lk-lanes of a row do this redundantly — broadcast loads)
  uint64_t b5[TOPK];
#pragma unroll
  for (int t = 0; t < TOPK; ++t)
    b5[t] = partial[((size_t)(m * NQB) * N + gi) * TOPK + t];
  for (int q = 1; q < NQB; ++q) {
    for (int t = 0; t < TOPK; ++t) {
      uint64_t key = partial[((size_t)(m * NQB + q) * N + gi) * TOPK + t];
      if (key >= b5[TOPK - 1]) break;
#pragma unroll
      for (int u = 0; u < TOPK; ++u) {
        const uint64_t cv = b5[u];
        if (key < cv) { b5[u] = key; key = cv; }
      }
    }
  }
  const uint64_t bound = b5[TOPK - 1];
  const float bz = __uint_as_float((uint32_t)(bound >> 32));

  const f32x4 zz = {0.0f, 0.0f, 0.0f, 0.0f};

  {  // prologue
    if (tid < 64)
      *(float4*)&sq_s[tid * 4] = *(const float4*)&ysq[mN + j0q + tid * 4];
    else if (tid < 128)
      *(float4*)&iv_s[(tid - 64) * 4] =
          *(const float4*)&inv[mN + j0q + (tid - 64) * 4];
    *(uint4*)(ybuf + sr * YSTRIDE + sc8) =
        *(const uint4*)(Xm + (size_t)(j0q + sr) * 128 + sc8);
    *(uint4*)(ybuf + 16 * YSTRIDE + sr * YSTRIDE + sc8) =
        *(const uint4*)(Xm + (size_t)(j0q + 16 + sr) * 128 + sc8);
    __syncthreads();
  }

#define PSCAN(T, BUF)                                                          \
  {                                                                            \
    const uint16_t* yp = (BUF) + lc * YSTRIDE + lk8;                           \
    const bf16x8 Y0 = *(const bf16x8*)(yp);                                    \
    const bf16x8 Y1 = *(const bf16x8*)(yp + 32);                               \
    const bf16x8 Y2 = *(const bf16x8*)(yp + 64);                               \
    const bf16x8 Y3 = *(const bf16x8*)(yp + 96);                               \
    f32x4 acc;  /* identical chain -> identical z bits */                      \
    acc = __builtin_amdgcn_mfma_f32_16x16x32_bf16(Y0, xf[0][0], zz, 0, 0, 0);  \
    acc = __builtin_amdgcn_mfma_f32_16x16x32_bf16(Y1, xf[1][0], acc, 0, 0, 0); \
    acc = __builtin_amdgcn_mfma_f32_16x16x32_bf16(Y2, xf[0][0], acc, 0, 0, 0); \
    acc = __builtin_amdgcn_mfma_f32_16x16x32_bf16(Y3, xf[1][0], acc, 0, 0, 0); \
    acc = __builtin_amdgcn_mfma_f32_16x16x32_bf16(Y0, xf[0][1], acc, 0, 0, 0); \
    acc = __builtin_amdgcn_mfma_f32_16x16x32_bf16(Y1, xf[1][1], acc, 0, 0, 0); \
    const float4 sq4 = *(const float4*)&sq_s[(T) * 16 + lk4];                  \
    const float4 iv4 = *(const float4*)&iv_s[(T) * 16 + lk4];                  \
    const int jb = j0q + (T) * 16;                                             \
    float zt[4];                                                               \
    _Pragma("unroll") for (int p = 0; p < 4; ++p) {                            \
      const float yc = (p == 0) ? sq4.x : (p == 1) ? sq4.y                     \
                      : (p == 2) ? sq4.z : sq4.w;                              \
      const float ic = (p == 0) ? iv4.x : (p == 1) ? iv4.y                     \
                      : (p == 2) ? iv4.z : iv4.w;                              \
      const float diff = fmaxf(xsq_i + yc - 2.0f * acc[p], 0.0f);              \
      zt[p] = fmaf(diff * inv2_i, ic, 1.0f);                                   \
    }                                                                          \
    const float zm = fminf(fminf(zt[0], zt[1]), fminf(zt[2], zt[3]));          \
    if (zm <= bz) {   /* necessary condition for key < bound */                \
      _Pragma("unroll") for (int p = 0; p < 4; ++p) {                          \
        const uint64_t key = ((uint64_t)__float_as_uint(zt[p]) << 32) |        \
                             (uint32_t)(jb + lk4 + p);                         \
        if (key < bound) {                                                     \
          const uint32_t slot = atomicAdd(&cnt[mN + gi], 1u);                  \
          if (slot < (uint32_t)CAP)                                            \
            rowlist[(size_t)(mN + gi) * CAP + slot] = key;                     \
        }                                                                      \
      }                                                                        \
    }                                                                          \
  }

#pragma unroll 1
  for (int T = 0; T < NT; T += 2) {
    const bool hn = (T + 2 < NT);
    uint4 s2, s3;
    if (hn) {
      s2 = *(const uint4*)(Xm + (size_t)(j0q + (T + 2) * 16 + sr) * 128 + sc8);
      s3 = *(const uint4*)(Xm + (size_t)(j0q + (T + 3) * 16 + sr) * 128 + sc8);
    }
    PSCAN(T, ybuf + (size_t)((T) & 3) * 16 * YSTRIDE)
    PSCAN(T + 1, ybuf + (size_t)((T + 1) & 3) * 16 * YSTRIDE)
    if (hn) {
      *(uint4*)(ybuf + (size_t)((T + 2) & 3) * 16 * YSTRIDE + sr * YSTRIDE + sc8) = s2;
      *(uint4*)(ybuf + (size_t)((T + 3) & 3) * 16 * YSTRIDE + sr * YSTRIDE + sc8) = s3;
    }
    __syncthreads();
  }
#undef PSCAN
}

// K2: merge quarter partials + survivors -> exact top-5; exact f32 pos_term;
// threefry sampling + exact negative distances + logsumexp.
__global__ __launch_bounds__(64) void k_neg(const float* __restrict__ Xa,
                                            const float* __restrict__ Xt,
                                            const float* __restrict__ ysq,
                                            const float* __restrict__ inv,
                                            const uint64_t* __restrict__ partial,
                                            const uint32_t* __restrict__ cnt,
                                            const uint64_t* __restrict__ rowlist,
                                            float* __restrict__ rowres) {
  const int m = blockIdx.y;
  const int i = blockIdx.x;
  const float* __restrict__ X = (m == 0) ? Xt : Xa;
  const uint32_t seed = (m == 0) ? 1u : 2u;  // key(1)=text, key(2)=audio
  const int lane = threadIdx.x;

  __shared__ float4 xi4[DIM / 4];
  __shared__ float posv[TOPK];
  if (lane < DIM / 4) xi4[lane] = ((const float4*)(X + (size_t)i * DIM))[lane];
  __syncthreads();

  // merge the 4 own-quarter sorted lists (uniform across lanes)
  uint64_t cur[TOPK];
#pragma unroll
  for (int t = 0; t < TOPK; ++t)
    cur[t] = partial[((size_t)(m * NQB) * N + i) * TOPK + t];
  for (int q = 1; q < NQB; ++q) {
    for (int t = 0; t < TOPK; ++t) {
      uint64_t key = partial[((size_t)(m * NQB + q) * N + i) * TOPK + t];
      if (key >= cur[TOPK - 1]) break;
#pragma unroll
      for (int u = 0; u < TOPK; ++u) {
        const uint64_t cv = cur[u];
        if (key < cv) { cur[u] = key; key = cv; }
      }
    }
  }
  // fold in survivors from the scan (unordered; order-independent result)
  {
    const uint32_t c_ = min(cnt[m * N + i], (uint32_t)CAP);
    for (uint32_t sv = 0; sv < c_; ++sv) {
      uint64_t key = rowlist[(size_t)(m * N + i) * CAP + sv];
      if (key < cur[TOPK - 1]) {
#pragma unroll
        for (int u = 0; u < TOPK; ++u) {
          const uint64_t cv = cur[u];
          if (key < cv) { cur[u] = key; key = cv; }
        }
      }
    }
  }

  const float ysq_i = ysq[m * N + i];
  const float inv_i = inv[m * N + i];

  // lanes 32..36: exact f32 distance for the 5 selected positives
  if (lane >= 32 && lane < 32 + TOPK) {
    const int t = lane - 32;
    const uint32_t c = (uint32_t)(cur[t] & 0xffffffffu);
    const float4* xc = (const float4*)(X + (size_t)c * DIM);
    float dot = 0.0f;
#pragma unroll
    for (int k = 0; k < DIM / 4; ++k) {
      const float4 a = xi4[k];
      const float4 b = xc[k];
      dot = fmaf(a.x, b.x, dot); dot = fmaf(a.y, b.y, dot);
      dot = fmaf(a.z, b.z, dot); dot = fmaf(a.w, b.w, dot);
    }
    const float diff = fmaxf(ysq_i + ysq[m * N + c] - 2.0f * dot, 0.0f);
    const float z = 1.0f + 2.0f * diff * inv_i * inv[m * N + c];
    posv[t] = -acosh_dev(z) / TAU_;
  }

  uint32_t pidx[TOPK];
#pragma unroll
  for (int t = 0; t < TOPK; ++t) pidx[t] = (uint32_t)(cur[t] & 0xffffffffu);

#define CSWAP(a, b)                                                           \
  { const uint32_t mn = pidx[a] < pidx[b] ? pidx[a] : pidx[b];                \
    const uint32_t mx = pidx[a] < pidx[b] ? pidx[b] : pidx[a];                \
    pidx[a] = mn; pidx[b] = mx; }
  CSWAP(0, 1) CSWAP(3, 4) CSWAP(2, 4) CSWAP(2, 3) CSWAP(1, 4)
  CSWAP(0, 3) CSWAP(0, 2) CSWAP(1, 3) CSWAP(1, 2)
#undef CSWAP

  float v = -1e30f;
  if (lane < NEGS) {
    const uint32_t f = (uint32_t)i * (uint32_t)NEGS + (uint32_t)lane;
    uint32_t c = sample_idx(seed, f);
#pragma unroll
    for (int t = 0; t < TOPK; ++t) c += (c >= pidx[t]) ? 1u : 0u;
    if (c != (uint32_t)i) {
      const float4* xc = (const float4*)(X + (size_t)c * DIM);
      float dot = 0.0f;
#pragma unroll
      for (int k = 0; k < DIM / 4; ++k) {
        const float4 a = xi4[k];
        const float4 b = xc[k];
        dot = fmaf(a.x, b.x, dot); dot = fmaf(a.y, b.y, dot);
        dot = fmaf(a.z, b.z, dot); dot = fmaf(a.w, b.w, dot);
      }
      const float diff = fmaxf(ysq_i + ysq[m * N + c] - 2.0f * dot, 0.0f);
      const float z = 1.0f + 2.0f * diff * inv_i * inv[m * N + c];
      v = -acosh_dev(z) / TAU_;
    }
  }

  __syncthreads();   // posv visible

  float vmax = v;
#pragma unroll
  for (int o = 32; o > 0; o >>= 1) vmax = fmaxf(vmax, __shfl_xor(vmax, o, 64));
  float e = expf(v - vmax);
  float ss = e;
#pragma unroll
  for (int o = 32; o > 0; o >>= 1) ss += __shfl_xor(ss, o, 64);

  if (lane == 0) {
    float vm = -1e30f;
#pragma unroll
    for (int t = 0; t < TOPK; ++t) vm = fmaxf(vm, posv[t]);
    float ps = 0.0f;
#pragma unroll
    for (int t = 0; t < TOPK; ++t) ps += expf(posv[t] - vm);
    const float pos = vm + logf(ps);
    rowres[m * N + i] = (vmax + logf(ss)) - pos;
  }
}

// K3: deterministic final reduce (f64 accumulation), out = 0.01 * mean
__global__ __launch_bounds__(256) void k_reduce(const float* __restrict__ rowres,
                                                float* __restrict__ out) {
  __shared__ double sh[256];
  double s = 0.0;
  for (int idx = threadIdx.x; idx < 2 * N; idx += 256) s += (double)rowres[idx];
  sh[threadIdx.x] = s;
  __syncthreads();
  for (int o = 128; o > 0; o >>= 1) {
    if (threadIdx.x < o) sh[threadIdx.x] += sh[threadIdx.x + o];
    __syncthreads();
  }
  if (threadIdx.x == 0) out[0] = (float)(0.01 * (sh[0] / (double)N));
}

extern "C" void kernel_launch(void* const* d_in, const int* in_sizes, int n_in,
                              void* d_out, int out_size, void* d_ws,
                              size_t ws_size, hipStream_t stream) {
  const float* Xa = (const float*)d_in[0];   // audio_embeds
  const float* Xt = (const float*)d_in[1];   // text_embeds
  float* out = (float*)d_out;

  // ws (~7.8 MB): ysq[2N] | inv[2N] | partial[2*4*N*5 u64] | rowres[2N]
  //               | cnt[2N u32] | rowlist[2N*CAP u64] | Xs[2*N*128 u16]
  float* ysq = (float*)d_ws;
  float* inv = ysq + 2 * N;
  uint64_t* partial = (uint64_t*)(inv + 2 * N);
  float* rowres = (float*)(partial + (size_t)2 * NQB * N * TOPK);
  uint32_t* cnt = (uint32_t*)(rowres + 2 * N);
  uint64_t* rowlist = (uint64_t*)(cnt + 2 * N);
  uint16_t* Xs = (uint16_t*)(rowlist + (size_t)2 * N * CAP);

  k_pre<<<dim3(N / 64, 2), 64, 0, stream>>>(Xa, Xt, Xs, ysq, inv, cnt);
  k_bound<<<dim3(N / RPB, NQB, 2), 256, 0, stream>>>(Xs, ysq, inv, partial);
  k_scan<<<dim3(N / RPB, 12, 2), 256, 0, stream>>>(Xs, ysq, inv, partial, cnt,
                                                   rowlist);
  k_neg<<<dim3(N, 2), 64, 0, stream>>>(Xa, Xt, ysq, inv, partial, cnt, rowlist,
                                       rowres);
  k_reduce<<<1, 256, 0, stream>>>(rowres, out);
}